// Round 8
// baseline (1386.052 us; speedup 1.0000x reference)
//
#include <hip/hip_runtime.h>
#include <float.h>

// RVQ inference via MFMA: B=16, C=64, N=4096, Q=8, K=8192, fp32 in/out.
// Round-13 deltas vs round-12 (1345us; MfmaUtil 16.9 / VALU 65.5 / occ 20):
//  - R12 confirmed MFMA/staging halving but dur only -8%: ~1000cy/slot stall
//    invariant to buffer depth. Remaining un-moved resource: occupancy stuck
//    at 2 waves/SIMD (LDS 67.5KB -> 2 blocks/CU). VALUBusy 65% = SIMD idles
//    35% with only 1 partner wave to cover ~120cy LDS latency + deps.
//  - Fix: LDS diet. P=64 (RES4 16KB) -> 47.4KB total -> 3 blocks/CU
//    = 3 waves/SIMD (+50% latency cover). Chip MFMA/pack totals unchanged.
//  - Staging source select (branchy per-iter q-crossover) replaced by uniform
//    byte CURSORS: +2048B/tile, quarter-jump via one scalar cmp; tail overrun
//    lands in allocated WL region (dummy tiles never consumed).
//  - Kept (R12-proven): hi-only GEMM, wave-private 16-code tiles, triple
//    buffer + counted vmcnt(6), XOR swizzle both-sides, per-quad packed
//    top-3, 4-wave top-4 merge, tiered TAU=0.2 fp32 rescore.
// ws: shalf (QK f32) | WH (QKC bf16-hi u16) | WL (unused, overrun pad) | loss.

typedef float f32x4 __attribute__((ext_vector_type(4)));
typedef short s16x8 __attribute__((ext_vector_type(8)));

constexpr int Bn=16, Cn=64, Nn=4096, Qn=8, Kn=8192;
constexpr int P=64;                     // points per block
constexpr int NPB = Nn/P;               // 64 n-blocks per batch row
constexpr int NBLK = Bn*Nn/P;           // 1024 blocks -> 3/CU (LDS-capped)
constexpr float TAU = 0.2f;             // rescore margin (~9.5 sigma)
constexpr int TILE_B = 2304;            // 2KB WH + 256B sv
constexpr size_t SH_F = (size_t)Qn*Kn;
constexpr size_t W_U  = (size_t)Qn*Kn*Cn;
// staging cursor jumps (bytes): end of a wave's 2048-code quarter -> start of
// next q's quarter
constexpr long QJ_H = (long)Kn*Cn*2 - 128L*2048;   // 786432
constexpr long QJ_S = (long)Kn*4     - 128L*64;    // 24576

union U8 { s16x8 v; unsigned short u[8]; };

__device__ __forceinline__ unsigned short bf_rtne(float x){
  unsigned int u = __float_as_uint(x);
  unsigned int r = (u + 0x7fffu + ((u>>16)&1u)) >> 16;
  return (unsigned short)r;
}

__device__ __forceinline__ void gl16(const void* g, void* l){
  __builtin_amdgcn_global_load_lds(
      (const __attribute__((address_space(1))) unsigned int*)g,
      (      __attribute__((address_space(3))) unsigned int*)l, 16, 0, 0);
}
__device__ __forceinline__ void gl4(const void* g, void* l){
  __builtin_amdgcn_global_load_lds(
      (const __attribute__((address_space(1))) unsigned int*)g,
      (      __attribute__((address_space(3))) unsigned int*)l, 4, 0, 0);
}

// Stage one 16-code tile (WH 2KB | sv 256B) from byte cursors into a
// wave-private LDS chunk. LDS dest LINEAR (wave-uniform base + lane*size);
// global SOURCE column carries the reader's XOR involution
// col' = col ^ ((row&7)<<4).  3 VMEM ops per stage (vmcnt accounting).
__device__ __forceinline__ void stage_tile(const char* spH, const char* spS,
                                           char* lds, int lane){
  int rl   = lane>>3;                    // row & 7
  int scol = ((lane&7) ^ rl) << 4;       // swizzled source column (bytes)
  const char* gH = spH + (size_t)rl*128 + (size_t)scol;
  gl16(gH,        lds);                  // WH rows 0..7
  gl16(gH + 1024, lds + 1024);           // WH rows 8..15
  gl4 (spS + (size_t)(lane & 15)*4, lds + 2048); // 16 floats (lanes 16+ dup)
}

__global__ __launch_bounds__(256) void prep_kernel(const float* __restrict__ cb,
    float* __restrict__ shalf, unsigned short* __restrict__ WH,
    unsigned short* __restrict__ WL, float* __restrict__ loss){
  int r = blockIdx.x*256 + threadIdx.x;
  if (r==0) *loss = 0.f;
  const float* row = cb + (size_t)r*Cn;
  float sq = 0.f;
  for (int c=0;c<Cn;++c){
    float v = row[c]; sq = fmaf(v,v,sq);
    WH[(size_t)r*Cn+c] = bf_rtne(v);
  }
  shalf[r] = -0.5f*sq;
}

__global__ __launch_bounds__(256)
__attribute__((amdgpu_waves_per_eu(3)))
void rvq_kernel(
    const float* __restrict__ x, const float* __restrict__ cb,
    const float* __restrict__ shalf,
    const unsigned short* __restrict__ WH, const unsigned short* __restrict__ WL,
    float* __restrict__ out, float* __restrict__ loss_acc){
  __shared__ float4 RES4[P*16];              // 16KB: res[p][g^(p&15)]
  __shared__ __align__(16) char ABUF[4][3][TILE_B]; // wave x tri-buf (27KB)
  __shared__ float  red_p1[4][P];            // packed (score|k11) per wave
  __shared__ float  red_p2[4][P];
  __shared__ float  red_p3[4][P];
  __shared__ int    bk_sh[P];
  __shared__ float  lsum[4];

  const int tid  = threadIdx.x;
  const int wave = tid>>6, lane = tid&63;
  const int quad = lane>>4, l16 = lane&15;
  const int b    = blockIdx.x / NPB;
  const int n0   = (blockIdx.x % NPB)*P;

  { // ---- RES init from x[B,C,N] (coalesced over p) ----
    int p = tid & (P-1), hc = tid>>6;        // 4 chan-groups of 4 float4s
    const float* xb = x + ((size_t)b*Cn)*Nn + n0 + p;
#pragma unroll
    for (int l=0;l<4;++l){
      int g = hc*4 + l;
      float4 v;
      v.x = xb[(size_t)(4*g+0)*Nn]; v.y = xb[(size_t)(4*g+1)*Nn];
      v.z = xb[(size_t)(4*g+2)*Nn]; v.w = xb[(size_t)(4*g+3)*Nn];
      RES4[p*16 + (g ^ (p&15))] = v;
    }
  }
  // staging cursors (wave-uniform): start at this wave's quarter of q=0
  const char* spH = (const char*)WH + (size_t)wave*2048*128;
  const char* spS = (const char*)shalf + (size_t)wave*2048*4;
  // prologue: stage tiles 0,1 into buffers 0,1; cursors advance to tile 2
  stage_tile(spH,        spS,      &ABUF[wave][0][0], lane);
  stage_tile(spH + 2048, spS + 64, &ABUF[wave][1][0], lane);
  spH += 2*2048; spS += 2*64;
  int cstg = 2;                              // tiles staged in current quarter
  __syncthreads();                           // drains vmcnt too

  float loss_pt = 0.f;
  int cur = 0;                               // rotates 0,1,2 across ALL q

  for (int q=0;q<Qn;++q){
    const float* sqq = shalf + (size_t)q*Kn;

    // ---- B-frags (4 ptiles, bf16-hi residual) in regs: 32 VGPR ----
    s16x8 Bh[4][2];
#pragma unroll
    for (int pt=0; pt<4; ++pt){
      int p = pt*16 + l16;
#pragma unroll
      for (int s=0;s<2;++s){
        int g0 = 8*s + quad*2;
        float4 ra = RES4[p*16 + ((g0  ) ^ (p&15))];
        float4 rb = RES4[p*16 + ((g0+1) ^ (p&15))];
        float f[8] = {ra.x,ra.y,ra.z,ra.w, rb.x,rb.y,rb.z,rb.w};
        U8 h;
#pragma unroll
        for (int j=0;j<8;++j) h.u[j]=bf_rtne(f[j]);
        Bh[pt][s]=h.v;
      }
    }

    // ---- scan this wave's 2048-code quarter; packed top-3 per point ----
    float s1[4], s2[4], s3[4];
#pragma unroll
    for (int pt=0;pt<4;++pt){ s1[pt]=-FLT_MAX; s2[pt]=-FLT_MAX; s3[pt]=-FLT_MAX; }

    int kb = wave*2048;
    const int sw   = (l16&7)<<4;
    const int aoff = l16*128;

    for (int kt=0; kt<128; ++kt){
      { // stage tile (kt+2 in staging stream) into buffer (cur+2)%3
        int sb = cur + 2; if (sb >= 3) sb -= 3;
        stage_tile(spH, spS, &ABUF[wave][sb][0], lane);
        spH += 2048; spS += 64;
        if (++cstg == 128){ cstg = 0; spH += QJ_H; spS += QJ_S; }
      }
      // T4 counted wait: 2 stages (6 loads) stay in flight; tile `cur` done.
      asm volatile("s_waitcnt vmcnt(6)" ::: "memory");
      __builtin_amdgcn_sched_barrier(0);

      const char* tb = &ABUF[wave][cur][0];
      s16x8 Ah0 = *(const s16x8*)(tb + aoff + (( 0 + quad*16) ^ sw));
      s16x8 Ah1 = *(const s16x8*)(tb + aoff + ((64 + quad*16) ^ sw));
      f32x4 sv  = *(const f32x4*)(tb + 2048 + quad*16);
      const unsigned int kloc = (unsigned int)((kb & 2047) | (quad<<2));

      // 4 independent 2-deep MFMA chains (hi-only distances)
      f32x4 a[4];
#pragma unroll
      for (int pt=0;pt<4;++pt)
        a[pt] = __builtin_amdgcn_mfma_f32_16x16x32_bf16(Ah0, Bh[pt][0], sv, 0,0,0);
#pragma unroll
      for (int pt=0;pt<4;++pt)
        a[pt] = __builtin_amdgcn_mfma_f32_16x16x32_bf16(Ah1, Bh[pt][1], a[pt], 0,0,0);

      // packed top-3 update: 4 VALU/score (and_or + fmax + 2x fmed3)
#pragma unroll
      for (int pt=0;pt<4;++pt){
#pragma unroll
        for (int r=0;r<4;++r){
          float pv = __uint_as_float((__float_as_uint(a[pt][r]) & 0xFFFFF800u)
                                     | (kloc + (unsigned)r));
          float n2 = __builtin_amdgcn_fmed3f(pv, s1[pt], s2[pt]);
          float n3 = __builtin_amdgcn_fmed3f(pv, s2[pt], s3[pt]);
          s1[pt] = fmaxf(s1[pt], pv); s2[pt] = n2; s3[pt] = n3;
        }
      }
      cur = cur + 1; if (cur >= 3) cur = 0;
      kb += 16;
    }

    // ---- cross-quad top-3 merge in packed domain (k travels in the bits) ----
#pragma unroll
    for (int pt=0;pt<4;++pt){
#pragma unroll
      for (int m=16; m<=32; m<<=1){
        float o1 = __shfl_xor(s1[pt], m, 64);
        float o2 = __shfl_xor(s2[pt], m, 64);
        float o3 = __shfl_xor(s3[pt], m, 64);
        float A  = fminf(s1[pt], o1);
        float n1 = fmaxf(s1[pt], o1);
        float Bv = fmaxf(s2[pt], o2);
        float D  = fmaxf(s3[pt], o3);
        float n2 = fmaxf(A, Bv);
        float n3 = fmaxf(fminf(A, Bv), D);
        s1[pt]=n1; s2[pt]=n2; s3[pt]=n3;
      }
      if (quad==0){
        int p = pt*16 + l16;
        red_p1[wave][p]=s1[pt]; red_p2[wave][p]=s2[pt]; red_p3[wave][p]=s3[pt];
      }
    }
    __syncthreads();

    // ---- per-point 4-wave TOP-4 merge (wave origin) + tiered rescore ----
    if (tid < P){
      float S1=-FLT_MAX,S2=-FLT_MAX,S3=-FLT_MAX,S4=-FLT_MAX;
      int   W1=0,W2=0,W3=0,W4=0;
#pragma unroll
      for (int w=0; w<4; ++w){
        float o[3] = { red_p1[w][tid], red_p2[w][tid], red_p3[w][tid] };
#pragma unroll
        for (int j=0;j<3;++j){
          float v = o[j];
          if (v > S1){ S4=S3;W4=W3; S3=S2;W3=W2; S2=S1;W2=W1; S1=v;W1=w; }
          else if (v > S2){ S4=S3;W4=W3; S3=S2;W3=W2; S2=v;W2=w; }
          else if (v > S3){ S4=S3;W4=W3; S3=v;W3=w; }
          else if (v > S4){ S4=v;W4=w; }
        }
      }
      int K1 = (W1<<11) | (int)(__float_as_uint(S1) & 2047u);
      if (S1 - S2 < TAU){   // near-tie: exact fp32 rescore, tiered to top-4
        int K2 = (W2<<11) | (int)(__float_as_uint(S2) & 2047u);
        float d1 = sqq[K1], d2 = sqq[K2];
        const float4* r1 = (const float4*)(cb + ((size_t)q*Kn + K1)*Cn);
        const float4* r2 = (const float4*)(cb + ((size_t)q*Kn + K2)*Cn);
#pragma unroll
        for (int g=0; g<16; ++g){
          float4 rv = RES4[tid*16 + (g ^ (tid&15))];
          float4 c1 = r1[g], c2 = r2[g];
          d1=fmaf(rv.x,c1.x,d1); d1=fmaf(rv.y,c1.y,d1);
          d1=fmaf(rv.z,c1.z,d1); d1=fmaf(rv.w,c1.w,d1);
          d2=fmaf(rv.x,c2.x,d2); d2=fmaf(rv.y,c2.y,d2);
          d2=fmaf(rv.z,c2.z,d2); d2=fmaf(rv.w,c2.w,d2);
        }
        if ( (d2 > d1) || (d2==d1 && K2<K1) ){ K1 = K2; d1 = d2; }
        if (S1 - S3 < TAU){
          int K3 = (W3<<11) | (int)(__float_as_uint(S3) & 2047u);
          float d3 = sqq[K3];
          const float4* r3 = (const float4*)(cb + ((size_t)q*Kn + K3)*Cn);
#pragma unroll
          for (int g=0; g<16; ++g){
            float4 rv = RES4[tid*16 + (g ^ (tid&15))];
            float4 c3 = r3[g];
            d3=fmaf(rv.x,c3.x,d3); d3=fmaf(rv.y,c3.y,d3);
            d3=fmaf(rv.z,c3.z,d3); d3=fmaf(rv.w,c3.w,d3);
          }
          if ( (d3 > d1) || (d3==d1 && K3<K1) ){ K1 = K3; d1 = d3; }
          if (S1 - S4 < TAU){
            int K4 = (W4<<11) | (int)(__float_as_uint(S4) & 2047u);
            float d4 = sqq[K4];
            const float4* r4 = (const float4*)(cb + ((size_t)q*Kn + K4)*Cn);
#pragma unroll
            for (int g=0; g<16; ++g){
              float4 rv = RES4[tid*16 + (g ^ (tid&15))];
              float4 c4 = r4[g];
              d4=fmaf(rv.x,c4.x,d4); d4=fmaf(rv.y,c4.y,d4);
              d4=fmaf(rv.z,c4.z,d4); d4=fmaf(rv.w,c4.w,d4);
            }
            if ( (d4 > d1) || (d4==d1 && K4<K1) ) K1 = K4;
          }
        }
      }
      bk_sh[tid]=K1;
      out[(size_t)(Bn*Cn*Nn) + (size_t)(b*Nn + n0 + tid)*Qn + q] = (float)K1;
    }
    __syncthreads();

    // ---- residual update (exact fp32, winner row L2-hot) + loss ----
    {
      int p = tid & (P-1), hc = tid>>6;
      int bk = bk_sh[p];
      const float4* crow = (const float4*)(cb + ((size_t)q*Kn + bk)*Cn) + hc*4;
#pragma unroll
      for (int l=0;l<4;++l){
        int g = hc*4 + l;
        float4 v = crow[l];
        int idx = p*16 + (g ^ (p&15));
        float4 rv = RES4[idx];
        rv.x-=v.x; rv.y-=v.y; rv.z-=v.z; rv.w-=v.w;
        RES4[idx]=rv;
        loss_pt = fmaf(rv.x,rv.x,loss_pt); loss_pt = fmaf(rv.y,rv.y,loss_pt);
        loss_pt = fmaf(rv.z,rv.z,loss_pt); loss_pt = fmaf(rv.w,rv.w,loss_pt);
      }
    }
    __syncthreads();
  } // q

  // ---- quantized = x - final residual (coalesced over p) ----
  {
    int p = tid & (P-1), hc = tid>>6;
    const float* xb = x + ((size_t)b*Cn)*Nn + n0 + p;
    float*       ob = out + ((size_t)b*Cn)*Nn + n0 + p;
#pragma unroll
    for (int l=0;l<4;++l){
      int g = hc*4+l, c = 4*g;
      float4 rv = RES4[p*16 + (g ^ (p&15))];
      ob[(size_t)(c+0)*Nn] = xb[(size_t)(c+0)*Nn] - rv.x;
      ob[(size_t)(c+1)*Nn] = xb[(size_t)(c+1)*Nn] - rv.y;
      ob[(size_t)(c+2)*Nn] = xb[(size_t)(c+2)*Nn] - rv.z;
      ob[(size_t)(c+3)*Nn] = xb[(size_t)(c+3)*Nn] - rv.w;
    }
  }
  float s = loss_pt;
#pragma unroll
  for (int off=32; off>0; off>>=1) s += __shfl_down(s, off, 64);
  if (lane==0) lsum[wave]=s;
  __syncthreads();
  if (tid==0) atomicAdd(loss_acc, lsum[0]+lsum[1]+lsum[2]+lsum[3]);
}

__global__ void final_kernel(const float* __restrict__ loss_acc,
                             float* __restrict__ out){
  out[(size_t)Bn*Cn*Nn + (size_t)Bn*Nn*Qn] =
      loss_acc[0] * (1.0f / ((float)Qn * Bn * Nn * Cn));
}

extern "C" void kernel_launch(void* const* d_in, const int* in_sizes, int n_in,
                              void* d_out, int out_size, void* d_ws, size_t ws_size,
                              hipStream_t stream) {
  const float* x  = (const float*)d_in[0];
  const float* cb = (const float*)d_in[1];
  float* out = (float*)d_out;
  float* ws  = (float*)d_ws;

  float* shalf = ws;
  unsigned short* WH = (unsigned short*)(ws + SH_F);
  unsigned short* WL = WH + W_U;           // unused (staging-overrun pad)
  float* loss = (float*)(WL + W_U);

  hipLaunchKernelGGL(prep_kernel, dim3((Qn*Kn)/256), dim3(256), 0, stream,
                     cb, shalf, WH, WL, loss);
  hipLaunchKernelGGL(rvq_kernel, dim3(NBLK), dim3(256), 0, stream,
                     x, cb, shalf, WH, WL, out, loss);
  hipLaunchKernelGGL(final_kernel, dim3(1), dim3(1), 0, stream, loss, out);
}

// Round 9
// 1109.337 us; speedup vs baseline: 1.2494x; 1.2494x over previous
//
#include <hip/hip_runtime.h>
#include <float.h>

// RVQ inference via MFMA: B=16, C=64, N=4096, Q=8, K=8192, fp32 in/out.
// Round-14 deltas vs round-13 (1386us; occ 26.7 != predicted 37 -> tri-buf
// grid 1024/3-resident left a 1.33-round tail; TLP experiment confounded):
//  - DOUBLE-buffer (ABUF 18KB, total LDS 38.2KB) -> 4 blocks/CU resident,
//    grid 1024 = exactly 4/CU, ZERO tail. 4 waves/SIMD = 2x R12's latency
//    cover. waves_per_eu(4) (budget 128 >> ~85 live).
//  - Scalarized staging: uwave=readfirstlane(wave) -> cursors/LDS bases
//    provably uniform (SGPR adds, not 64b VGPR adds); per-lane offsets
//    hoisted. K-loop unrolled x2 (dbuf period): cur arithmetic gone, ds_read
//    addresses loop-invariant, counted vmcnt(3) per half.
//  - Numerics UNCHANGED from R12/R13 (proven): hi-only GEMM, packed 11-bit
//    per-quad top-3, 4-wave top-4 merge, tiered TAU=0.2 fp32 rescore.
// ws: shalf (QK f32) | WH (QKC bf16-hi u16) | WL (unused, overrun pad) | loss.

typedef float f32x4 __attribute__((ext_vector_type(4)));
typedef short s16x8 __attribute__((ext_vector_type(8)));

constexpr int Bn=16, Cn=64, Nn=4096, Qn=8, Kn=8192;
constexpr int P=64;                     // points per block
constexpr int NPB = Nn/P;               // 64 n-blocks per batch row
constexpr int NBLK = Bn*Nn/P;           // 1024 blocks = exactly 4/CU
constexpr float TAU = 0.2f;             // rescore margin (~9.5 sigma)
constexpr int TILE_B = 2304;            // 2KB WH + 256B sv
constexpr size_t SH_F = (size_t)Qn*Kn;
constexpr size_t W_U  = (size_t)Qn*Kn*Cn;
// staging cursor jumps (bytes): end of a wave's 2048-code quarter -> start of
// next q's quarter
constexpr long QJ_H = (long)Kn*Cn*2 - 128L*2048;   // 786432
constexpr long QJ_S = (long)Kn*4     - 128L*64;    // 24576

union U8 { s16x8 v; unsigned short u[8]; };

__device__ __forceinline__ unsigned short bf_rtne(float x){
  unsigned int u = __float_as_uint(x);
  unsigned int r = (u + 0x7fffu + ((u>>16)&1u)) >> 16;
  return (unsigned short)r;
}

__device__ __forceinline__ void gl16(const void* g, void* l){
  __builtin_amdgcn_global_load_lds(
      (const __attribute__((address_space(1))) unsigned int*)g,
      (      __attribute__((address_space(3))) unsigned int*)l, 16, 0, 0);
}
__device__ __forceinline__ void gl4(const void* g, void* l){
  __builtin_amdgcn_global_load_lds(
      (const __attribute__((address_space(1))) unsigned int*)g,
      (      __attribute__((address_space(3))) unsigned int*)l, 4, 0, 0);
}

// Stage one 16-code tile (WH 2KB | sv 256B). lds/spH/spS are wave-uniform
// (derived from readfirstlane'd wave -> SGPR addressing); per-lane SOURCE
// column carries the reader's XOR involution col' = col ^ ((row&7)<<4).
// 3 VMEM ops per stage (vmcnt accounting).
__device__ __forceinline__ void stage_tile(const char* spH, const char* spS,
                                           char* lds, int lane){
  int rl   = lane>>3;                    // row & 7
  int scol = ((lane&7) ^ rl) << 4;       // swizzled source column (bytes)
  const char* gH = spH + (size_t)rl*128 + (size_t)scol;
  gl16(gH,        lds);                  // WH rows 0..7
  gl16(gH + 1024, lds + 1024);           // WH rows 8..15
  gl4 (spS + (size_t)(lane & 15)*4, lds + 2048); // 16 floats (lanes 16+ dup)
}

__global__ __launch_bounds__(256) void prep_kernel(const float* __restrict__ cb,
    float* __restrict__ shalf, unsigned short* __restrict__ WH,
    unsigned short* __restrict__ WL, float* __restrict__ loss){
  int r = blockIdx.x*256 + threadIdx.x;
  if (r==0) *loss = 0.f;
  const float* row = cb + (size_t)r*Cn;
  float sq = 0.f;
  for (int c=0;c<Cn;++c){
    float v = row[c]; sq = fmaf(v,v,sq);
    WH[(size_t)r*Cn+c] = bf_rtne(v);
  }
  shalf[r] = -0.5f*sq;
}

__global__ __launch_bounds__(256)
__attribute__((amdgpu_waves_per_eu(4)))
void rvq_kernel(
    const float* __restrict__ x, const float* __restrict__ cb,
    const float* __restrict__ shalf,
    const unsigned short* __restrict__ WH, const unsigned short* __restrict__ WL,
    float* __restrict__ out, float* __restrict__ loss_acc){
  __shared__ float4 RES4[P*16];              // 16KB: res[p][g^(p&15)]
  __shared__ __align__(16) char ABUF[4][2][TILE_B]; // wave x dbuf (18KB)
  __shared__ float  red_p1[4][P];            // packed (score|k11) per wave
  __shared__ float  red_p2[4][P];
  __shared__ float  red_p3[4][P];
  __shared__ int    bk_sh[P];
  __shared__ float  lsum[4];

  const int tid  = threadIdx.x;
  const int wave = tid>>6, lane = tid&63;
  const int quad = lane>>4, l16 = lane&15;
  const int b    = blockIdx.x / NPB;
  const int n0   = (blockIdx.x % NPB)*P;
  // wave is uniform across the wave: tell the compiler so all staging/LDS
  // base arithmetic goes scalar (SGPR) instead of 64-bit VGPR adds.
  const int uwave = __builtin_amdgcn_readfirstlane(wave);

  { // ---- RES init from x[B,C,N] (coalesced over p) ----
    int p = tid & (P-1), hc = tid>>6;        // 4 chan-groups of 4 float4s
    const float* xb = x + ((size_t)b*Cn)*Nn + n0 + p;
#pragma unroll
    for (int l=0;l<4;++l){
      int g = hc*4 + l;
      float4 v;
      v.x = xb[(size_t)(4*g+0)*Nn]; v.y = xb[(size_t)(4*g+1)*Nn];
      v.z = xb[(size_t)(4*g+2)*Nn]; v.w = xb[(size_t)(4*g+3)*Nn];
      RES4[p*16 + (g ^ (p&15))] = v;
    }
  }
  // staging cursors (scalar): start at this wave's quarter of q=0
  const char* spH = (const char*)WH + (size_t)uwave*2048*128;
  const char* spS = (const char*)shalf + (size_t)uwave*2048*4;
  char* const buf0 = &ABUF[uwave][0][0];
  char* const buf1 = &ABUF[uwave][1][0];
  // prologue: stage tile 0 into buf0 (q-init barrier below drains it)
  stage_tile(spH, spS, buf0, lane);
  spH += 2048; spS += 64;
  int cstg = 1;                              // tiles staged in current quarter
  __syncthreads();                           // drains vmcnt too

  float loss_pt = 0.f;

  for (int q=0;q<Qn;++q){
    const float* sqq = shalf + (size_t)q*Kn;

    // ---- B-frags (4 ptiles, bf16-hi residual) in regs: 32 VGPR ----
    s16x8 Bh[4][2];
#pragma unroll
    for (int pt=0; pt<4; ++pt){
      int p = pt*16 + l16;
#pragma unroll
      for (int s=0;s<2;++s){
        int g0 = 8*s + quad*2;
        float4 ra = RES4[p*16 + ((g0  ) ^ (p&15))];
        float4 rb = RES4[p*16 + ((g0+1) ^ (p&15))];
        float f[8] = {ra.x,ra.y,ra.z,ra.w, rb.x,rb.y,rb.z,rb.w};
        U8 h;
#pragma unroll
        for (int j=0;j<8;++j) h.u[j]=bf_rtne(f[j]);
        Bh[pt][s]=h.v;
      }
    }

    // ---- scan this wave's 2048-code quarter; packed top-3 per point ----
    float s1[4], s2[4], s3[4];
#pragma unroll
    for (int pt=0;pt<4;++pt){ s1[pt]=-FLT_MAX; s2[pt]=-FLT_MAX; s3[pt]=-FLT_MAX; }

    const int sw   = (l16&7)<<4;
    const int rc0  = l16*128 + ((quad*16) ^ sw);   // Ah0 byte offset in tile
    const int rcS  = 2048 + quad*16;               // sv byte offset in tile
    unsigned kloc = (unsigned)(quad<<2);           // 11-bit local k cursor

    for (int kt=0; kt<128; kt+=2){
      // ---------- half A: compute buf0, stage into buf1 ----------
      stage_tile(spH, spS, buf1, lane);
      spH += 2048; spS += 64;
      if (++cstg == 128){ cstg = 0; spH += QJ_H; spS += QJ_S; }
      asm volatile("s_waitcnt vmcnt(3)" ::: "memory");  // buf0's stage done
      __builtin_amdgcn_sched_barrier(0);
      {
        s16x8 Ah0 = *(const s16x8*)(buf0 + rc0);
        s16x8 Ah1 = *(const s16x8*)(buf0 + (rc0 ^ 64));
        f32x4 sv  = *(const f32x4*)(buf0 + rcS);
        f32x4 a[4];
#pragma unroll
        for (int pt=0;pt<4;++pt)
          a[pt] = __builtin_amdgcn_mfma_f32_16x16x32_bf16(Ah0, Bh[pt][0], sv, 0,0,0);
#pragma unroll
        for (int pt=0;pt<4;++pt)
          a[pt] = __builtin_amdgcn_mfma_f32_16x16x32_bf16(Ah1, Bh[pt][1], a[pt], 0,0,0);
#pragma unroll
        for (int pt=0;pt<4;++pt){
#pragma unroll
          for (int r=0;r<4;++r){
            float pv = __uint_as_float((__float_as_uint(a[pt][r]) & 0xFFFFF800u)
                                       | (kloc + (unsigned)r));
            float n2 = __builtin_amdgcn_fmed3f(pv, s1[pt], s2[pt]);
            float n3 = __builtin_amdgcn_fmed3f(pv, s2[pt], s3[pt]);
            s1[pt] = fmaxf(s1[pt], pv); s2[pt] = n2; s3[pt] = n3;
          }
        }
      }
      kloc += 16;

      // ---------- half B: compute buf1, stage into buf0 ----------
      stage_tile(spH, spS, buf0, lane);
      spH += 2048; spS += 64;
      if (++cstg == 128){ cstg = 0; spH += QJ_H; spS += QJ_S; }
      asm volatile("s_waitcnt vmcnt(3)" ::: "memory");  // buf1's stage done
      __builtin_amdgcn_sched_barrier(0);
      {
        s16x8 Ah0 = *(const s16x8*)(buf1 + rc0);
        s16x8 Ah1 = *(const s16x8*)(buf1 + (rc0 ^ 64));
        f32x4 sv  = *(const f32x4*)(buf1 + rcS);
        f32x4 a[4];
#pragma unroll
        for (int pt=0;pt<4;++pt)
          a[pt] = __builtin_amdgcn_mfma_f32_16x16x32_bf16(Ah0, Bh[pt][0], sv, 0,0,0);
#pragma unroll
        for (int pt=0;pt<4;++pt)
          a[pt] = __builtin_amdgcn_mfma_f32_16x16x32_bf16(Ah1, Bh[pt][1], a[pt], 0,0,0);
#pragma unroll
        for (int pt=0;pt<4;++pt){
#pragma unroll
          for (int r=0;r<4;++r){
            float pv = __uint_as_float((__float_as_uint(a[pt][r]) & 0xFFFFF800u)
                                       | (kloc + (unsigned)r));
            float n2 = __builtin_amdgcn_fmed3f(pv, s1[pt], s2[pt]);
            float n3 = __builtin_amdgcn_fmed3f(pv, s2[pt], s3[pt]);
            s1[pt] = fmaxf(s1[pt], pv); s2[pt] = n2; s3[pt] = n3;
          }
        }
      }
      kloc += 16;
    }

    // ---- cross-quad top-3 merge in packed domain (k travels in the bits) ----
#pragma unroll
    for (int pt=0;pt<4;++pt){
#pragma unroll
      for (int m=16; m<=32; m<<=1){
        float o1 = __shfl_xor(s1[pt], m, 64);
        float o2 = __shfl_xor(s2[pt], m, 64);
        float o3 = __shfl_xor(s3[pt], m, 64);
        float A  = fminf(s1[pt], o1);
        float n1 = fmaxf(s1[pt], o1);
        float Bv = fmaxf(s2[pt], o2);
        float D  = fmaxf(s3[pt], o3);
        float n2 = fmaxf(A, Bv);
        float n3 = fmaxf(fminf(A, Bv), D);
        s1[pt]=n1; s2[pt]=n2; s3[pt]=n3;
      }
      if (quad==0){
        int p = pt*16 + l16;
        red_p1[wave][p]=s1[pt]; red_p2[wave][p]=s2[pt]; red_p3[wave][p]=s3[pt];
      }
    }
    __syncthreads();

    // ---- per-point 4-wave TOP-4 merge (wave origin) + tiered rescore ----
    if (tid < P){
      float S1=-FLT_MAX,S2=-FLT_MAX,S3=-FLT_MAX,S4=-FLT_MAX;
      int   W1=0,W2=0,W3=0,W4=0;
#pragma unroll
      for (int w=0; w<4; ++w){
        float o[3] = { red_p1[w][tid], red_p2[w][tid], red_p3[w][tid] };
#pragma unroll
        for (int j=0;j<3;++j){
          float v = o[j];
          if (v > S1){ S4=S3;W4=W3; S3=S2;W3=W2; S2=S1;W2=W1; S1=v;W1=w; }
          else if (v > S2){ S4=S3;W4=W3; S3=S2;W3=W2; S2=v;W2=w; }
          else if (v > S3){ S4=S3;W4=W3; S3=v;W3=w; }
          else if (v > S4){ S4=v;W4=w; }
        }
      }
      int K1 = (W1<<11) | (int)(__float_as_uint(S1) & 2047u);
      if (S1 - S2 < TAU){   // near-tie: exact fp32 rescore, tiered to top-4
        int K2 = (W2<<11) | (int)(__float_as_uint(S2) & 2047u);
        float d1 = sqq[K1], d2 = sqq[K2];
        const float4* r1 = (const float4*)(cb + ((size_t)q*Kn + K1)*Cn);
        const float4* r2 = (const float4*)(cb + ((size_t)q*Kn + K2)*Cn);
#pragma unroll
        for (int g=0; g<16; ++g){
          float4 rv = RES4[tid*16 + (g ^ (tid&15))];
          float4 c1 = r1[g], c2 = r2[g];
          d1=fmaf(rv.x,c1.x,d1); d1=fmaf(rv.y,c1.y,d1);
          d1=fmaf(rv.z,c1.z,d1); d1=fmaf(rv.w,c1.w,d1);
          d2=fmaf(rv.x,c2.x,d2); d2=fmaf(rv.y,c2.y,d2);
          d2=fmaf(rv.z,c2.z,d2); d2=fmaf(rv.w,c2.w,d2);
        }
        if ( (d2 > d1) || (d2==d1 && K2<K1) ){ K1 = K2; d1 = d2; }
        if (S1 - S3 < TAU){
          int K3 = (W3<<11) | (int)(__float_as_uint(S3) & 2047u);
          float d3 = sqq[K3];
          const float4* r3 = (const float4*)(cb + ((size_t)q*Kn + K3)*Cn);
#pragma unroll
          for (int g=0; g<16; ++g){
            float4 rv = RES4[tid*16 + (g ^ (tid&15))];
            float4 c3 = r3[g];
            d3=fmaf(rv.x,c3.x,d3); d3=fmaf(rv.y,c3.y,d3);
            d3=fmaf(rv.z,c3.z,d3); d3=fmaf(rv.w,c3.w,d3);
          }
          if ( (d3 > d1) || (d3==d1 && K3<K1) ){ K1 = K3; d1 = d3; }
          if (S1 - S4 < TAU){
            int K4 = (W4<<11) | (int)(__float_as_uint(S4) & 2047u);
            float d4 = sqq[K4];
            const float4* r4 = (const float4*)(cb + ((size_t)q*Kn + K4)*Cn);
#pragma unroll
            for (int g=0; g<16; ++g){
              float4 rv = RES4[tid*16 + (g ^ (tid&15))];
              float4 c4 = r4[g];
              d4=fmaf(rv.x,c4.x,d4); d4=fmaf(rv.y,c4.y,d4);
              d4=fmaf(rv.z,c4.z,d4); d4=fmaf(rv.w,c4.w,d4);
            }
            if ( (d4 > d1) || (d4==d1 && K4<K1) ) K1 = K4;
          }
        }
      }
      bk_sh[tid]=K1;
      out[(size_t)(Bn*Cn*Nn) + (size_t)(b*Nn + n0 + tid)*Qn + q] = (float)K1;
    }
    __syncthreads();

    // ---- residual update (exact fp32, winner row L2-hot) + loss ----
    {
      int p = tid & (P-1), hc = tid>>6;
      int bk = bk_sh[p];
      const float4* crow = (const float4*)(cb + ((size_t)q*Kn + bk)*Cn) + hc*4;
#pragma unroll
      for (int l=0;l<4;++l){
        int g = hc*4 + l;
        float4 v = crow[l];
        int idx = p*16 + (g ^ (p&15));
        float4 rv = RES4[idx];
        rv.x-=v.x; rv.y-=v.y; rv.z-=v.z; rv.w-=v.w;
        RES4[idx]=rv;
        loss_pt = fmaf(rv.x,rv.x,loss_pt); loss_pt = fmaf(rv.y,rv.y,loss_pt);
        loss_pt = fmaf(rv.z,rv.z,loss_pt); loss_pt = fmaf(rv.w,rv.w,loss_pt);
      }
    }
    __syncthreads();
  } // q

  // ---- quantized = x - final residual (coalesced over p) ----
  {
    int p = tid & (P-1), hc = tid>>6;
    const float* xb = x + ((size_t)b*Cn)*Nn + n0 + p;
    float*       ob = out + ((size_t)b*Cn)*Nn + n0 + p;
#pragma unroll
    for (int l=0;l<4;++l){
      int g = hc*4+l, c = 4*g;
      float4 rv = RES4[p*16 + (g ^ (p&15))];
      ob[(size_t)(c+0)*Nn] = xb[(size_t)(c+0)*Nn] - rv.x;
      ob[(size_t)(c+1)*Nn] = xb[(size_t)(c+1)*Nn] - rv.y;
      ob[(size_t)(c+2)*Nn] = xb[(size_t)(c+2)*Nn] - rv.z;
      ob[(size_t)(c+3)*Nn] = xb[(size_t)(c+3)*Nn] - rv.w;
    }
  }
  float s = loss_pt;
#pragma unroll
  for (int off=32; off>0; off>>=1) s += __shfl_down(s, off, 64);
  if (lane==0) lsum[wave]=s;
  __syncthreads();
  if (tid==0) atomicAdd(loss_acc, lsum[0]+lsum[1]+lsum[2]+lsum[3]);
}

__global__ void final_kernel(const float* __restrict__ loss_acc,
                             float* __restrict__ out){
  out[(size_t)Bn*Cn*Nn + (size_t)Bn*Nn*Qn] =
      loss_acc[0] * (1.0f / ((float)Qn * Bn * Nn * Cn));
}

extern "C" void kernel_launch(void* const* d_in, const int* in_sizes, int n_in,
                              void* d_out, int out_size, void* d_ws, size_t ws_size,
                              hipStream_t stream) {
  const float* x  = (const float*)d_in[0];
  const float* cb = (const float*)d_in[1];
  float* out = (float*)d_out;
  float* ws  = (float*)d_ws;

  float* shalf = ws;
  unsigned short* WH = (unsigned short*)(ws + SH_F);
  unsigned short* WL = WH + W_U;           // unused (staging-overrun pad)
  float* loss = (float*)(WL + W_U);

  hipLaunchKernelGGL(prep_kernel, dim3((Qn*Kn)/256), dim3(256), 0, stream,
                     cb, shalf, WH, WL, loss);
  hipLaunchKernelGGL(rvq_kernel, dim3(NBLK), dim3(256), 0, stream,
                     x, cb, shalf, WH, WL, out, loss);
  hipLaunchKernelGGL(final_kernel, dim3(1), dim3(1), 0, stream, loss, out);
}